// Round 1
// baseline (389.802 us; speedup 1.0000x reference)
//
#include <hip/hip_runtime.h>
#include <hip/hip_bf16.h>

#define B_DIM 128
#define S_DIM 64
#define DIN   2048
#define DOUT  2048
#define NLAYERS 64

#define BM 128
#define BN 128
#define BK 64

typedef __bf16 bf16_t;
typedef __attribute__((ext_vector_type(8))) bf16_t bf16x8;
typedef __attribute__((ext_vector_type(4))) float f32x4;

// Order positions by layer so same-layer tiles are scheduled adjacently
// (keeps the 16.8MB layer weight panel resident in LLC across positions).
__global__ void sort_positions(const int* __restrict__ layer_idx, int* __restrict__ perm) {
    if (threadIdx.x == 0) {
        int p = 0;
        for (int l = 0; l < NLAYERS; ++l)
            for (int s = 0; s < S_DIM; ++s)
                if (layer_idx[s] == l) perm[p++] = s;
    }
}

__device__ __forceinline__ bf16x8 cvt8(const float* __restrict__ g) {
    f32x4 a = *(const f32x4*)g;
    f32x4 b = *(const f32x4*)(g + 4);
    bf16x8 r;
    r[0] = (bf16_t)a[0]; r[1] = (bf16_t)a[1]; r[2] = (bf16_t)a[2]; r[3] = (bf16_t)a[3];
    r[4] = (bf16_t)b[0]; r[5] = (bf16_t)b[1]; r[6] = (bf16_t)b[2]; r[7] = (bf16_t)b[3];
    return r;
}

// One 128x128 output tile per block: rows = all of B (128), cols = 128 of D_OUT.
// A = x[:, s, :]   (row stride S*DIN),  B = weight[layer][nb*128 .. ) (row stride DIN)
// out[b][o] = sum_k A[b][k] * B[o][k]  -> both operands row-major, K-contiguous.
__launch_bounds__(256, 2)
__global__ void flex_linear_gemm(const float* __restrict__ x,
                                 const float* __restrict__ w,
                                 const int* __restrict__ layer_idx,
                                 const int* __restrict__ perm,
                                 float* __restrict__ out) {
    __shared__ bf16_t Alds[BM * BK];  // XOR-swizzled row-major [128][64]
    __shared__ bf16_t Blds[BN * BK];

    const int nb = blockIdx.x;          // output column block (16 of them)
    const int s  = perm[blockIdx.y];    // position, layer-sorted
    const int layer = layer_idx[s];

    const float* Ag = x + (size_t)s * DIN;
    const float* Bg = w + (size_t)layer * (size_t)(DOUT * DIN) + (size_t)(nb * BN) * DIN;

    const int tid  = threadIdx.x;
    const int lane = tid & 63;
    const int wave = tid >> 6;
    const int wr = (wave >> 1) * 64;    // wave row offset in tile
    const int wc = (wave & 1) * 64;     // wave col offset in tile

    f32x4 acc[4][4] = {};

    const int lrow = lane & 15;
    const int lk   = (lane >> 4) * 8;

    for (int kb = 0; kb < DIN / BK; ++kb) {
        const int k0 = kb * BK;
        __syncthreads();  // protect LDS from previous iteration's readers
        // ---- stage A and B tiles: fp32 global -> cvt bf16 -> LDS (swizzled) ----
        #pragma unroll
        for (int i = 0; i < 4; ++i) {
            const int c   = tid + 256 * i;   // chunk id 0..1023
            const int row = c >> 3;          // 0..127
            const int kc  = c & 7;           // 8-elem chunk within BK
            const int off = (row * BK + kc * 8) ^ ((row & 7) << 3);
            *(bf16x8*)&Alds[off] = cvt8(Ag + (size_t)row * (S_DIM * DIN) + k0 + kc * 8);
            *(bf16x8*)&Blds[off] = cvt8(Bg + (size_t)row * DIN + k0 + kc * 8);
        }
        __syncthreads();
        // ---- MFMA over BK=64 (two K=32 substeps) ----
        #pragma unroll
        for (int kk = 0; kk < 2; ++kk) {
            const int klo = kk * 32 + lk;
            bf16x8 af[4], bfr[4];
            #pragma unroll
            for (int m = 0; m < 4; ++m) {
                const int row = wr + m * 16 + lrow;
                af[m] = *(const bf16x8*)&Alds[(row * BK + klo) ^ ((row & 7) << 3)];
            }
            #pragma unroll
            for (int n = 0; n < 4; ++n) {
                const int row = wc + n * 16 + lrow;
                bfr[n] = *(const bf16x8*)&Blds[(row * BK + klo) ^ ((row & 7) << 3)];
            }
            #pragma unroll
            for (int m = 0; m < 4; ++m)
                #pragma unroll
                for (int n = 0; n < 4; ++n)
                    acc[m][n] = __builtin_amdgcn_mfma_f32_16x16x32_bf16(af[m], bfr[n], acc[m][n], 0, 0, 0);
        }
    }

    // ---- epilogue: C/D layout col = lane&15, row = (lane>>4)*4 + r ----
    float* Og = out + (size_t)s * DOUT + (size_t)(nb * BN);
    #pragma unroll
    for (int m = 0; m < 4; ++m) {
        const int rb = wr + m * 16 + (lane >> 4) * 4;  // b index base
        #pragma unroll
        for (int r = 0; r < 4; ++r) {
            float* orow = Og + (size_t)(rb + r) * (S_DIM * DOUT);
            #pragma unroll
            for (int n = 0; n < 4; ++n)
                orow[wc + n * 16 + (lane & 15)] = acc[m][n][r];
        }
    }
}

extern "C" void kernel_launch(void* const* d_in, const int* in_sizes, int n_in,
                              void* d_out, int out_size, void* d_ws, size_t ws_size,
                              hipStream_t stream) {
    const float* x         = (const float*)d_in[0];
    const float* w         = (const float*)d_in[1];
    const int*   layer_idx = (const int*)d_in[2];
    float*       out       = (float*)d_out;
    int*         perm      = (int*)d_ws;   // 64 ints

    sort_positions<<<1, 64, 0, stream>>>(layer_idx, perm);
    dim3 grid(DOUT / BN, S_DIM);
    flex_linear_gemm<<<grid, dim3(256), 0, stream>>>(x, w, layer_idx, perm, out);
}

// Round 2
// 305.573 us; speedup vs baseline: 1.2756x; 1.2756x over previous
//
#include <hip/hip_runtime.h>
#include <hip/hip_bf16.h>

#define B_DIM 128
#define S_DIM 64
#define DIN   2048
#define DOUT  2048
#define NLAYERS 64

#define BM 128
#define BN 128
#define BK 64
#define NK (DIN / BK)

typedef __bf16 bf16_t;
typedef __attribute__((ext_vector_type(8))) bf16_t bf16x8;
typedef __attribute__((ext_vector_type(4))) float f32x4;

// Parallel rank sort: perm = positions ordered by (layer, s).
// Replaces the serial 1-thread counting sort (4096 serial global reads).
__global__ void rank_sort(const int* __restrict__ layer_idx, int* __restrict__ perm) {
    __shared__ int L[S_DIM];
    const int s = threadIdx.x;
    L[s] = layer_idx[s];
    __syncthreads();
    const int mine = L[s];
    int rank = 0;
    #pragma unroll
    for (int t = 0; t < S_DIM; ++t) {
        const int lt = L[t];
        rank += (lt < mine || (lt == mine && t < s)) ? 1 : 0;
    }
    perm[rank] = s;
}

// One 128x128 output tile per block. T14 pipeline: issue global loads for
// tile k+1 BEFORE the ds_read+MFMA of tile k; cvt+ds_write after the
// read-barrier. Single 32KB LDS buffer; the staging registers are the
// second buffer.
__launch_bounds__(256, 2)
__global__ void flex_linear_gemm(const float* __restrict__ x,
                                 const float* __restrict__ w,
                                 const int* __restrict__ layer_idx,
                                 const int* __restrict__ perm,
                                 float* __restrict__ out) {
    __shared__ bf16_t Alds[BM * BK];  // XOR-swizzled row-major [128][64]
    __shared__ bf16_t Blds[BN * BK];

    const int nb = blockIdx.x;          // output column block (16)
    const int s  = perm[blockIdx.y];    // position, layer-sorted
    const int layer = layer_idx[s];

    const float* Ag = x + (size_t)s * DIN;
    const float* Bg = w + (size_t)layer * (size_t)(DOUT * DIN) + (size_t)(nb * BN) * DIN;

    const int tid  = threadIdx.x;
    const int lane = tid & 63;
    const int wave = tid >> 6;
    const int wr = (wave >> 1) * 64;
    const int wc = (wave & 1) * 64;
    const int lrow = lane & 15;
    const int lk   = (lane >> 4) * 8;

    // ---- hoisted addresses ----
    int offW[4];
    const float* pA[4];
    const float* pB[4];
    #pragma unroll
    for (int i = 0; i < 4; ++i) {
        const int row = (tid >> 3) + 32 * i;   // 0..127
        const int kc8 = (tid & 7) * 8;         // 8-elem chunk within BK
        offW[i] = (row * BK + kc8) ^ ((row & 7) << 3);
        pA[i] = Ag + (size_t)row * (S_DIM * DIN) + kc8;
        pB[i] = Bg + (size_t)row * DIN + kc8;
    }
    int offA[2][4], offB[2][4];
    #pragma unroll
    for (int kk = 0; kk < 2; ++kk) {
        #pragma unroll
        for (int m = 0; m < 4; ++m) {
            const int ra = wr + m * 16 + lrow;
            const int rb = wc + m * 16 + lrow;
            offA[kk][m] = (ra * BK + kk * 32 + lk) ^ ((ra & 7) << 3);
            offB[kk][m] = (rb * BK + kk * 32 + lk) ^ ((rb & 7) << 3);
        }
    }

    f32x4 RA[8], RB[8];       // in-flight fp32 staging (64 VGPRs)
    f32x4 acc[4][4] = {};

    auto issue = [&](int kb) {
        const int koff = kb * BK;
        #pragma unroll
        for (int i = 0; i < 4; ++i) {
            const float* a = pA[i] + koff;
            const float* b = pB[i] + koff;
            RA[2 * i]     = *(const f32x4*)a;
            RA[2 * i + 1] = *(const f32x4*)(a + 4);
            RB[2 * i]     = *(const f32x4*)b;
            RB[2 * i + 1] = *(const f32x4*)(b + 4);
        }
    };
    auto cvt_write = [&]() {
        #pragma unroll
        for (int i = 0; i < 4; ++i) {
            bf16x8 va, vb;
            #pragma unroll
            for (int j = 0; j < 4; ++j) {
                va[j]     = (bf16_t)RA[2 * i][j];
                va[j + 4] = (bf16_t)RA[2 * i + 1][j];
                vb[j]     = (bf16_t)RB[2 * i][j];
                vb[j + 4] = (bf16_t)RB[2 * i + 1][j];
            }
            *(bf16x8*)&Alds[offW[i]] = va;
            *(bf16x8*)&Blds[offW[i]] = vb;
        }
    };
    auto compute = [&]() {
        #pragma unroll
        for (int kk = 0; kk < 2; ++kk) {
            bf16x8 af[4], bfr[4];
            #pragma unroll
            for (int m = 0; m < 4; ++m) {
                af[m]  = *(const bf16x8*)&Alds[offA[kk][m]];
                bfr[m] = *(const bf16x8*)&Blds[offB[kk][m]];
            }
            #pragma unroll
            for (int m = 0; m < 4; ++m)
                #pragma unroll
                for (int n = 0; n < 4; ++n)
                    acc[m][n] = __builtin_amdgcn_mfma_f32_16x16x32_bf16(af[m], bfr[n], acc[m][n], 0, 0, 0);
        }
    };

    // ---- pipelined main loop: 2 barriers per K-step ----
    issue(0);
    cvt_write();                 // waits for k=0 loads (once)
    for (int kb = 0; kb < NK - 1; ++kb) {
        __syncthreads();         // tile kb visible to all waves
        issue(kb + 1);           // loads in flight during compute of kb
        compute();               // reads tile kb
        __syncthreads();         // all waves done reading
        cvt_write();             // overwrite LDS with tile kb+1
    }
    __syncthreads();
    compute();                   // last tile

    // ---- epilogue: C/D layout col = lane&15, row = (lane>>4)*4 + r ----
    float* Og = out + (size_t)s * DOUT + (size_t)(nb * BN);
    #pragma unroll
    for (int m = 0; m < 4; ++m) {
        const int rb = wr + m * 16 + (lane >> 4) * 4;
        #pragma unroll
        for (int r = 0; r < 4; ++r) {
            float* orow = Og + (size_t)(rb + r) * (S_DIM * DOUT);
            #pragma unroll
            for (int n = 0; n < 4; ++n)
                orow[wc + n * 16 + (lane & 15)] = acc[m][n][r];
        }
    }
}

extern "C" void kernel_launch(void* const* d_in, const int* in_sizes, int n_in,
                              void* d_out, int out_size, void* d_ws, size_t ws_size,
                              hipStream_t stream) {
    const float* x         = (const float*)d_in[0];
    const float* w         = (const float*)d_in[1];
    const int*   layer_idx = (const int*)d_in[2];
    float*       out       = (float*)d_out;
    int*         perm      = (int*)d_ws;   // 64 ints

    rank_sort<<<1, S_DIM, 0, stream>>>(layer_idx, perm);
    dim3 grid(DOUT / BN, S_DIM);
    flex_linear_gemm<<<grid, dim3(256), 0, stream>>>(x, w, layer_idx, perm, out);
}

// Round 3
// 277.021 us; speedup vs baseline: 1.4071x; 1.1031x over previous
//
#include <hip/hip_runtime.h>
#include <hip/hip_bf16.h>

#define B_DIM 128
#define S_DIM 64
#define DIN   2048
#define DOUT  2048
#define NLAYERS 64

#define BM 128
#define BN 128
#define BK 64
#define NK (DIN / BK)
#define NTILES (S_DIM * (DOUT / BN))   // 1024
#define NXCD 8

typedef __bf16 bf16_t;
typedef __attribute__((ext_vector_type(8))) bf16_t bf16x8;
typedef __attribute__((ext_vector_type(4))) float f32x4;

// Parallel rank sort: perm = positions ordered by (layer, s).
__global__ void rank_sort(const int* __restrict__ layer_idx, int* __restrict__ perm) {
    __shared__ int L[S_DIM];
    const int s = threadIdx.x;
    L[s] = layer_idx[s];
    __syncthreads();
    const int mine = L[s];
    int rank = 0;
    #pragma unroll
    for (int t = 0; t < S_DIM; ++t) {
        const int lt = L[t];
        rank += (lt < mine || (lt == mine && t < s)) ? 1 : 0;
    }
    perm[rank] = s;
}

// One 128x128 output tile per block. T14 pipeline (issue-early/consume-late)
// + T1 XCD-chunked swizzle: each XCD owns 8 consecutive sorted positions x
// all 16 nb-tiles, so x-slice sharers (16 nb-blocks) and duplicate-layer
// weight sharers are co-resident on ONE XCD's L2.
__launch_bounds__(256, 2)
__global__ void flex_linear_gemm(const float* __restrict__ x,
                                 const float* __restrict__ w,
                                 const int* __restrict__ layer_idx,
                                 const int* __restrict__ perm,
                                 float* __restrict__ out) {
    __shared__ bf16_t Alds[BM * BK];  // XOR-swizzled row-major [128][64]
    __shared__ bf16_t Blds[BN * BK];

    // ---- XCD-chunked swizzle (1024 % 8 == 0 -> bijective) ----
    const int orig = blockIdx.x;          // dispatch order round-robins XCDs
    const int xcd  = orig & (NXCD - 1);
    const int slot = orig >> 3;           // 0..127, ascending within each XCD
    const int tile = xcd * (NTILES / NXCD) + slot;
    const int yy   = tile >> 4;           // sorted-position rank 0..63
    const int nb   = tile & 15;           // output column block

    const int s  = perm[yy];
    const int layer = layer_idx[s];

    const float* Ag = x + (size_t)s * DIN;
    const float* Bg = w + (size_t)layer * (size_t)(DOUT * DIN) + (size_t)(nb * BN) * DIN;

    const int tid  = threadIdx.x;
    const int lane = tid & 63;
    const int wave = tid >> 6;
    const int wr = (wave >> 1) * 64;
    const int wc = (wave & 1) * 64;
    const int lrow = lane & 15;
    const int lk   = (lane >> 4) * 8;

    // ---- hoisted addresses ----
    int offW[4];
    const float* pA[4];
    const float* pB[4];
    #pragma unroll
    for (int i = 0; i < 4; ++i) {
        const int row = (tid >> 3) + 32 * i;   // 0..127
        const int kc8 = (tid & 7) * 8;         // 8-elem chunk within BK
        offW[i] = (row * BK + kc8) ^ ((row & 7) << 3);
        pA[i] = Ag + (size_t)row * (S_DIM * DIN) + kc8;
        pB[i] = Bg + (size_t)row * DIN + kc8;
    }
    int offA[2][4], offB[2][4];
    #pragma unroll
    for (int kk = 0; kk < 2; ++kk) {
        #pragma unroll
        for (int m = 0; m < 4; ++m) {
            const int ra = wr + m * 16 + lrow;
            const int rb = wc + m * 16 + lrow;
            offA[kk][m] = (ra * BK + kk * 32 + lk) ^ ((ra & 7) << 3);
            offB[kk][m] = (rb * BK + kk * 32 + lk) ^ ((rb & 7) << 3);
        }
    }

    f32x4 RA[8], RB[8];       // in-flight fp32 staging (64 VGPRs)
    f32x4 acc[4][4] = {};

    auto issue = [&](int kb) {
        const int koff = kb * BK;
        #pragma unroll
        for (int i = 0; i < 4; ++i) {
            const float* a = pA[i] + koff;
            const float* b = pB[i] + koff;
            RA[2 * i]     = *(const f32x4*)a;
            RA[2 * i + 1] = *(const f32x4*)(a + 4);
            RB[2 * i]     = *(const f32x4*)b;
            RB[2 * i + 1] = *(const f32x4*)(b + 4);
        }
    };
    auto cvt_write = [&]() {
        #pragma unroll
        for (int i = 0; i < 4; ++i) {
            bf16x8 va, vb;
            #pragma unroll
            for (int j = 0; j < 4; ++j) {
                va[j]     = (bf16_t)RA[2 * i][j];
                va[j + 4] = (bf16_t)RA[2 * i + 1][j];
                vb[j]     = (bf16_t)RB[2 * i][j];
                vb[j + 4] = (bf16_t)RB[2 * i + 1][j];
            }
            *(bf16x8*)&Alds[offW[i]] = va;
            *(bf16x8*)&Blds[offW[i]] = vb;
        }
    };
    auto compute = [&]() {
        #pragma unroll
        for (int kk = 0; kk < 2; ++kk) {
            bf16x8 af[4], bfr[4];
            #pragma unroll
            for (int m = 0; m < 4; ++m) {
                af[m]  = *(const bf16x8*)&Alds[offA[kk][m]];
                bfr[m] = *(const bf16x8*)&Blds[offB[kk][m]];
            }
            #pragma unroll
            for (int m = 0; m < 4; ++m)
                #pragma unroll
                for (int n = 0; n < 4; ++n)
                    acc[m][n] = __builtin_amdgcn_mfma_f32_16x16x32_bf16(af[m], bfr[n], acc[m][n], 0, 0, 0);
        }
    };

    // ---- pipelined main loop: 2 barriers per K-step ----
    issue(0);
    cvt_write();                 // waits for k=0 loads (once)
    for (int kb = 0; kb < NK - 1; ++kb) {
        __syncthreads();         // tile kb visible to all waves
        issue(kb + 1);           // loads in flight during compute of kb
        compute();               // reads tile kb
        __syncthreads();         // all waves done reading
        cvt_write();             // overwrite LDS with tile kb+1
    }
    __syncthreads();
    compute();                   // last tile

    // ---- epilogue: C/D layout col = lane&15, row = (lane>>4)*4 + r ----
    float* Og = out + (size_t)s * DOUT + (size_t)(nb * BN);
    #pragma unroll
    for (int m = 0; m < 4; ++m) {
        const int rb = wr + m * 16 + (lane >> 4) * 4;
        #pragma unroll
        for (int r = 0; r < 4; ++r) {
            float* orow = Og + (size_t)(rb + r) * (S_DIM * DOUT);
            #pragma unroll
            for (int n = 0; n < 4; ++n)
                orow[wc + n * 16 + (lane & 15)] = acc[m][n][r];
        }
    }
}

extern "C" void kernel_launch(void* const* d_in, const int* in_sizes, int n_in,
                              void* d_out, int out_size, void* d_ws, size_t ws_size,
                              hipStream_t stream) {
    const float* x         = (const float*)d_in[0];
    const float* w         = (const float*)d_in[1];
    const int*   layer_idx = (const int*)d_in[2];
    float*       out       = (float*)d_out;
    int*         perm      = (int*)d_ws;   // 64 ints

    rank_sort<<<1, S_DIM, 0, stream>>>(layer_idx, perm);
    flex_linear_gemm<<<NTILES, dim3(256), 0, stream>>>(x, w, layer_idx, perm, out);
}